// Round 1
// baseline (544.417 us; speedup 1.0000x reference)
//
#include <hip/hip_runtime.h>
#include <hip/hip_bf16.h>
#include <cstdint>
#include <cstddef>
#include <type_traits>

typedef _Float16 half8 __attribute__((ext_vector_type(8)));
typedef _Float16 half4v __attribute__((ext_vector_type(4)));
typedef float float4v __attribute__((ext_vector_type(4)));

// ---------------- CSR build ----------------

__global__ void k_zero_int(int* __restrict__ p, int n) {
  int i = blockIdx.x * blockDim.x + threadIdx.x;
  if (i < n) p[i] = 0;
}

__global__ void k_count(const int* __restrict__ dst, int* __restrict__ cnt, int E) {
  int e = blockIdx.x * blockDim.x + threadIdx.x;
  if (e < E) atomicAdd(&cnt[dst[e]], 1);
}

// hierarchical exclusive scan: local (per-1024 block) -> sums -> fixup
__global__ __launch_bounds__(1024) void k_scan_local(const int* __restrict__ cnt,
                                                     int* __restrict__ rowp,
                                                     int* __restrict__ bsum, int n) {
  __shared__ int sm[1024];
  int tid = threadIdx.x;
  int i = blockIdx.x * 1024 + tid;
  int v = (i < n) ? cnt[i] : 0;
  sm[tid] = v;
  __syncthreads();
  for (int off = 1; off < 1024; off <<= 1) {
    int t = (tid >= off) ? sm[tid - off] : 0;
    __syncthreads();
    sm[tid] += t;
    __syncthreads();
  }
  if (i < n) rowp[i] = sm[tid] - v;  // exclusive (pre-fixup)
  if (tid == 1023) bsum[blockIdx.x] = sm[1023];
}

__global__ __launch_bounds__(1024) void k_scan_sums(int* __restrict__ bsum, int nb) {
  __shared__ int sm[1024];
  int tid = threadIdx.x;
  int v = (tid < nb) ? bsum[tid] : 0;
  sm[tid] = v;
  __syncthreads();
  for (int off = 1; off < 1024; off <<= 1) {
    int t = (tid >= off) ? sm[tid - off] : 0;
    __syncthreads();
    sm[tid] += t;
    __syncthreads();
  }
  if (tid < nb) bsum[tid] = sm[tid] - v;  // exclusive
}

// fixup + cursor copy + dinv, fused
__global__ void k_finalize(int* __restrict__ rowp, const int* __restrict__ bsum,
                           const int* __restrict__ cnt, int* __restrict__ cursor,
                           float* __restrict__ dinv, int n, int E) {
  int i = blockIdx.x * blockDim.x + threadIdx.x;
  if (i < n) {
    int v = rowp[i] + bsum[i >> 10];
    rowp[i] = v;
    cursor[i] = v;
    dinv[i] = rsqrtf((float)(cnt[i] + 1));  // +1 self loop
  }
  if (i == 0) rowp[n] = E;
}

__global__ void k_fill(const int* __restrict__ src, const int* __restrict__ dst,
                       int* __restrict__ cursor, int* __restrict__ csr_src, int E) {
  int e = blockIdx.x * blockDim.x + threadIdx.x;
  if (e < E) {
    int pos = atomicAdd(&cursor[dst[e]], 1);
    csr_src[pos] = src[e];
  }
}

// ---------------- fused weight convert+transpose (3 matrices in one launch) --------

__global__ void k_w_convert_all(const float* __restrict__ W1, const float* __restrict__ Wg1,
                                const float* __restrict__ Wg2, _Float16* __restrict__ W1t,
                                _Float16* __restrict__ Wg1t, _Float16* __restrict__ Wg2t,
                                int in_dim, int hid) {
  int idx = blockIdx.x * blockDim.x + threadIdx.x;
  int n1 = in_dim * hid;
  int n2 = hid * hid;
  if (idx < n1) {
    int n = idx / in_dim, k = idx - n * in_dim;
    W1t[idx] = (_Float16)W1[(size_t)k * hid + n];
  } else if (idx < n1 + n2) {
    int i2 = idx - n1;
    int n = i2 / hid, k = i2 - n * hid;
    Wg1t[i2] = (_Float16)Wg1[(size_t)k * hid + n];
  } else if (idx < n1 + 2 * n2) {
    int i2 = idx - n1 - n2;
    int n = i2 / hid, k = i2 - n * hid;
    Wg2t[i2] = (_Float16)Wg2[(size_t)k * hid + n];
  }
}

// ---------------- fp16 MFMA GEMM, 64x128 tile, dbuf + 2-deep register prefetch -------
// out[M,N] = act(A[M,K] @ Bt^T [+ bias]) [* rowscale[r]]; Bt fp16 [N,K].
// 256 threads = 4 waves (2x2), each wave 32x64 (acc 2x4), 8 MFMA/k-step.
// KEY: prefetch stages keep the RAW loaded type (fp32 for A of GEMM1) and convert
// only at LDS-write time, so the vmcnt wait sits at the ds_write, not loop-top.
// 2-deep staging (tiles k+1 and k+2 in flight) -> wait is counted (newest loads
// stay outstanding), window ~2 iterations instead of ~0. Stage indices are
// compile-time via manual 2x unroll (runtime-indexed ext_vector arrays -> scratch).
// NOTE: no device lambdas (clang-22 frontend crash in round 3).

#define LDSS 40  // LDS row stride in halves (32 + 8 pad -> <=2-way banks, free)

template <typename AT>
__device__ __forceinline__ void issue_tile(const AT* __restrict__ Apt,
                                           const _Float16* __restrict__ Bp0,
                                           const _Float16* __restrict__ Bp1,
                                           int k0, bool oka,
                                           float4v& a0, float4v& a1, half8& ah,
                                           half8& b0, half8& b1) {
  if constexpr (std::is_same_v<AT, float>) {
    if (oka) {
      a0 = *(const float4v*)(Apt + k0);
      a1 = *(const float4v*)(Apt + k0 + 4);
    }
  } else {
    if (oka) ah = *(const half8*)(Apt + k0);
  }
  b0 = *(const half8*)(Bp0 + k0);
  b1 = *(const half8*)(Bp1 + k0);
}

template <typename AT>
__device__ __forceinline__ void write_stage(_Float16* __restrict__ AsW,
                                            _Float16* __restrict__ BsW0,
                                            _Float16* __restrict__ BsW1,
                                            int nbuf, int abufstep, int bbufstep,
                                            const float4v& a0, const float4v& a1,
                                            const half8& ah, const half8& b0,
                                            const half8& b1) {
  half8 va;
  if constexpr (std::is_same_v<AT, float>) {
    va[0] = (_Float16)a0[0]; va[1] = (_Float16)a0[1];
    va[2] = (_Float16)a0[2]; va[3] = (_Float16)a0[3];
    va[4] = (_Float16)a1[0]; va[5] = (_Float16)a1[1];
    va[6] = (_Float16)a1[2]; va[7] = (_Float16)a1[3];
  } else {
    va = ah;
  }
  *(half8*)(AsW + nbuf * abufstep) = va;
  *(half8*)(BsW0 + nbuf * bbufstep) = b0;
  *(half8*)(BsW1 + nbuf * bbufstep) = b1;
}

__device__ __forceinline__ void mfma_step(const _Float16* __restrict__ Ab,
                                          const _Float16* __restrict__ Bb,
                                          int wm, int wn, int quad, int l15,
                                          float4v (&acc)[2][4]) {
  half8 af[2], bf[4];
#pragma unroll
  for (int i = 0; i < 2; ++i)
    af[i] = *(const half8*)(Ab + (wm + i * 16 + l15) * LDSS + quad * 8);
#pragma unroll
  for (int j = 0; j < 4; ++j)
    bf[j] = *(const half8*)(Bb + (wn + j * 16 + l15) * LDSS + quad * 8);
#pragma unroll
  for (int i = 0; i < 2; ++i)
#pragma unroll
    for (int j = 0; j < 4; ++j)
      acc[i][j] = __builtin_amdgcn_mfma_f32_16x16x32_f16(af[i], bf[j], acc[i][j], 0, 0, 0);
}

template <typename AT, int RELU, int BIAS, int SCALE>
__global__ __launch_bounds__(256, 4) void k_gemm_mfma(const AT* __restrict__ A,
                                                      const _Float16* __restrict__ Bt,
                                                      const float* __restrict__ bias,
                                                      const float* __restrict__ rowscale,
                                                      _Float16* __restrict__ out,
                                                      int M, int N, int K) {
  __shared__ _Float16 Asm[2][64 * LDSS];
  __shared__ _Float16 Bsm[2][128 * LDSS];
  const int tid = threadIdx.x;
  const int bm = blockIdx.y * 64;
  const int bn = blockIdx.x * 128;
  const int wave = tid >> 6;
  const int wm = (wave >> 1) * 32;   // 0 or 32
  const int wn = (wave & 1) * 64;    // 0 or 64
  const int quad = (tid & 63) >> 4;
  const int l15 = tid & 15;

  // staging assignments
  const int ar = tid >> 2;           // 0..63  A row
  const int ac = (tid & 3) * 8;      // A chunk (halves)

  const int gra = bm + ar;
  const bool oka = gra < M;
  const AT* Apt = A + (size_t)gra * K + ac;
  const int br_0 = tid >> 2, bc_0 = (tid & 3) * 8;
  const int br_1 = (tid + 256) >> 2, bc_1 = ((tid + 256) & 3) * 8;
  const _Float16* Bp0 = Bt + (size_t)(bn + br_0) * K + bc_0;
  const _Float16* Bp1 = Bt + (size_t)(bn + br_1) * K + bc_1;

  _Float16* AsW = &Asm[0][0] + ar * LDSS + ac;
  _Float16* BsW0 = &Bsm[0][0] + br_0 * LDSS + bc_0;
  _Float16* BsW1 = &Bsm[0][0] + br_1 * LDSS + bc_1;
  const int abufstep = 64 * LDSS;
  const int bbufstep = 128 * LDSS;

  float4v acc[2][4];
#pragma unroll
  for (int i = 0; i < 2; ++i)
#pragma unroll
    for (int j = 0; j < 4; ++j) acc[i][j] = (float4v){0.f, 0.f, 0.f, 0.f};

  // 2-deep prefetch stages (raw loaded type; zero-init covers !oka rows)
  float4v a00 = {}, a01 = {}, a10 = {}, a11 = {};
  half8 ah0 = {}, ah1 = {};
  half8 b00 = {}, b01 = {}, b10 = {}, b11 = {};

  const int nk = K >> 5;

  // prologue: issue tiles 0 and 1; write tile 0 -> LDS buf 0
  issue_tile<AT>(Apt, Bp0, Bp1, 0, oka, a00, a01, ah0, b00, b01);
  if (nk > 1) issue_tile<AT>(Apt, Bp0, Bp1, 32, oka, a10, a11, ah1, b10, b11);
  write_stage<AT>(AsW, BsW0, BsW1, 0, abufstep, bbufstep, a00, a01, ah0, b00, b01);

  int buf = 0;
  int kt = 0;
  while (true) {
    // even body: stage0 holds tile kt (already in LDS); issue tile kt+2 -> stage0
    __syncthreads();
    if (kt + 2 < nk)
      issue_tile<AT>(Apt, Bp0, Bp1, (kt + 2) << 5, oka, a00, a01, ah0, b00, b01);
    mfma_step(&Asm[0][0] + buf * abufstep, &Bsm[0][0] + buf * bbufstep, wm, wn, quad, l15, acc);
    if (kt + 1 < nk)
      write_stage<AT>(AsW, BsW0, BsW1, buf ^ 1, abufstep, bbufstep, a10, a11, ah1, b10, b11);
    buf ^= 1;
    if (++kt >= nk) break;

    // odd body: stage1 holds tile kt (already in LDS); issue tile kt+2 -> stage1
    __syncthreads();
    if (kt + 2 < nk)
      issue_tile<AT>(Apt, Bp0, Bp1, (kt + 2) << 5, oka, a10, a11, ah1, b10, b11);
    mfma_step(&Asm[0][0] + buf * abufstep, &Bsm[0][0] + buf * bbufstep, wm, wn, quad, l15, acc);
    if (kt + 1 < nk)
      write_stage<AT>(AsW, BsW0, BsW1, buf ^ 1, abufstep, bbufstep, a00, a01, ah0, b00, b01);
    buf ^= 1;
    if (++kt >= nk) break;
  }

  // epilogue: C/D layout col=lane&15, row=quad*4+reg
#pragma unroll
  for (int j = 0; j < 4; ++j) {
    int c = bn + wn + j * 16 + l15;
    float bv = BIAS ? bias[c] : 0.f;
#pragma unroll
    for (int i = 0; i < 2; ++i) {
      int rbase = bm + wm + i * 16 + quad * 4;
      float4v a = acc[i][j];
#pragma unroll
      for (int reg = 0; reg < 4; ++reg) {
        int r = rbase + reg;
        if (r < M) {
          float v = a[reg] + bv;
          if (RELU) v = fmaxf(v, 0.f);
          if (SCALE) v *= rowscale[r];
          out[(size_t)r * N + c] = (_Float16)v;
        }
      }
    }
  }
}

// ---------------- fp32 tiled GEMM (tail): C = act(A @ B + bias) ----------------

template <int RELU, int BIAS>
__global__ __launch_bounds__(256) void k_gemm(const float* __restrict__ A,
                                              const float* __restrict__ B,
                                              const float* __restrict__ bias,
                                              float* __restrict__ C,
                                              int M, int N, int K) {
  __shared__ float As[16][68];
  __shared__ float Bs[16][68];
  const int bm = blockIdx.y * 64;
  const int bn = blockIdx.x * 64;
  const int tid = threadIdx.x;
  const int tr = (tid >> 4) << 2;
  const int tc = (tid & 15) << 2;
  const int lm  = tid >> 2;
  const int lk  = (tid & 3) << 2;
  const int lk2 = tid >> 4;
  const int ln  = (tid & 15) << 2;
  const bool arow_ok = (bm + lm) < M;
  const float* Aptr = A + (size_t)(bm + lm) * K + lk;
  const float* Bptr = B + (size_t)lk2 * N + bn + ln;
  float acc[4][4] = {};
  for (int k0 = 0; k0 < K; k0 += 16) {
    float4 a4 = make_float4(0.f, 0.f, 0.f, 0.f);
    if (arow_ok) a4 = *(const float4*)(Aptr + k0);
    float4 b4 = *(const float4*)(Bptr + (size_t)k0 * N);
    As[lk + 0][lm] = a4.x;
    As[lk + 1][lm] = a4.y;
    As[lk + 2][lm] = a4.z;
    As[lk + 3][lm] = a4.w;
    *(float4*)&Bs[lk2][ln] = b4;
    __syncthreads();
#pragma unroll
    for (int k = 0; k < 16; ++k) {
      float4 av = *(const float4*)&As[k][tr];
      float4 bv = *(const float4*)&Bs[k][tc];
      float a[4] = {av.x, av.y, av.z, av.w};
      float b[4] = {bv.x, bv.y, bv.z, bv.w};
#pragma unroll
      for (int i = 0; i < 4; ++i)
#pragma unroll
        for (int j = 0; j < 4; ++j) acc[i][j] += a[i] * b[j];
    }
    __syncthreads();
  }
  float bias_v[4] = {0.f, 0.f, 0.f, 0.f};
  if (BIAS) {
    float4 bb = *(const float4*)(bias + bn + tc);
    bias_v[0] = bb.x; bias_v[1] = bb.y; bias_v[2] = bb.z; bias_v[3] = bb.w;
  }
#pragma unroll
  for (int i = 0; i < 4; ++i) {
    int r = bm + tr + i;
    if (r < M) {
      float4 o;
      o.x = acc[i][0] + bias_v[0];
      o.y = acc[i][1] + bias_v[1];
      o.z = acc[i][2] + bias_v[2];
      o.w = acc[i][3] + bias_v[3];
      if (RELU) {
        o.x = fmaxf(o.x, 0.f); o.y = fmaxf(o.y, 0.f);
        o.z = fmaxf(o.z, 0.f); o.w = fmaxf(o.w, 0.f);
      }
      *(float4*)&C[(size_t)r * N + bn + tc] = o;
    }
  }
}

// ---------------- GCN aggregation (gather, one wave/node, 256 feats) ----------------
// t is PRE-SCALED: t'[i] = t[i]*dinv[i].  out[i] = (t'[i] + sum t'[src]) * dinv[i] + b

template <typename OT>
__global__ __launch_bounds__(256) void k_agg(const _Float16* __restrict__ t,
                                             const int* __restrict__ row_ptr,
                                             const int* __restrict__ csr_src,
                                             const float* __restrict__ dinv,
                                             const float* __restrict__ bias,
                                             OT* __restrict__ out, int n_nodes) {
  int w = (int)((blockIdx.x * 256 + threadIdx.x) >> 6);
  int lane = threadIdx.x & 63;
  if (w >= n_nodes) return;
  float di = dinv[w];
  half4v v = *(const half4v*)(t + (size_t)w * 256 + lane * 4);
  float ax = (float)v[0], ay = (float)v[1], az = (float)v[2], aw = (float)v[3];
  int e0 = row_ptr[w], e1 = row_ptr[w + 1];
  int e = e0;
  for (; e + 4 <= e1; e += 4) {
    int s0 = csr_src[e];
    int s1 = csr_src[e + 1];
    int s2 = csr_src[e + 2];
    int s3 = csr_src[e + 3];
    half4v u0 = *(const half4v*)(t + (size_t)s0 * 256 + lane * 4);
    half4v u1 = *(const half4v*)(t + (size_t)s1 * 256 + lane * 4);
    half4v u2 = *(const half4v*)(t + (size_t)s2 * 256 + lane * 4);
    half4v u3 = *(const half4v*)(t + (size_t)s3 * 256 + lane * 4);
    ax += (float)u0[0] + (float)u1[0] + (float)u2[0] + (float)u3[0];
    ay += (float)u0[1] + (float)u1[1] + (float)u2[1] + (float)u3[1];
    az += (float)u0[2] + (float)u1[2] + (float)u2[2] + (float)u3[2];
    aw += (float)u0[3] + (float)u1[3] + (float)u2[3] + (float)u3[3];
  }
  for (; e < e1; ++e) {
    int s = csr_src[e];
    half4v u = *(const half4v*)(t + (size_t)s * 256 + lane * 4);
    ax += (float)u[0]; ay += (float)u[1]; az += (float)u[2]; aw += (float)u[3];
  }
  const float4 b = ((const float4*)bias)[lane];
  if constexpr (std::is_same_v<OT, float>) {
    float4 o;
    o.x = ax * di + b.x; o.y = ay * di + b.y;
    o.z = az * di + b.z; o.w = aw * di + b.w;
    ((float4*)(out + (size_t)w * 256))[lane] = o;
  } else {
    half4v o;
    o[0] = (_Float16)(ax * di + b.x); o[1] = (_Float16)(ay * di + b.y);
    o[2] = (_Float16)(az * di + b.z); o[3] = (_Float16)(aw * di + b.w);
    *(half4v*)(out + (size_t)w * 256 + lane * 4) = o;
  }
}

// ---------------- classifier: out[M,2] = h[M,K] @ Wc[K,2] + bc ----------------

__global__ __launch_bounds__(256) void k_cls(const float* __restrict__ h,
                                             const float* __restrict__ Wc,
                                             const float* __restrict__ bc,
                                             float* __restrict__ out, int M, int K) {
  __shared__ float w[512];
  for (int i = threadIdx.x; i < 2 * K; i += 256) w[i] = Wc[i];
  __syncthreads();
  int i = blockIdx.x * 256 + threadIdx.x;
  if (i >= M) return;
  float a0 = bc[0], a1 = bc[1];
  const float* hr = h + (size_t)i * K;
  for (int k = 0; k < K; ++k) {
    float a = hr[k];
    a0 += a * w[2 * k];
    a1 += a * w[2 * k + 1];
  }
  out[2 * i] = a0;
  out[2 * i + 1] = a1;
}

// ---------------- launch ----------------

extern "C" void kernel_launch(void* const* d_in, const int* in_sizes, int n_in,
                              void* d_out, int out_size, void* d_ws, size_t ws_size,
                              hipStream_t stream) {
  const float* x   = (const float*)d_in[0];
  const int*   ei  = (const int*)d_in[1];
  const float* W1  = (const float*)d_in[2];
  const float* b1  = (const float*)d_in[3];
  const float* Wg1 = (const float*)d_in[4];
  const float* bg1 = (const float*)d_in[5];
  const float* Wg2 = (const float*)d_in[6];
  const float* bg2 = (const float*)d_in[7];
  const float* W2  = (const float*)d_in[8];
  const float* b2  = (const float*)d_in[9];
  const float* Wc  = (const float*)d_in[10];
  const float* bc  = (const float*)d_in[11];
  float* out = (float*)d_out;

  const int hid     = in_sizes[3];            // 256
  const int in_dim  = in_sizes[2] / hid;      // 768
  const int out_dim = in_sizes[9];            // 128
  const int N       = in_sizes[0] / in_dim;   // 50000
  const int E       = in_sizes[1] / 2;        // 800000
  const int Batch   = out_size / 2;           // 1024

  const int* srcI = ei;
  const int* dstI = ei + E;

  char* ws = (char*)d_ws;
  size_t off = 0;
  auto alloc = [&](size_t bytes) -> void* {
    void* p = ws + off;
    off = (off + bytes + 255) & ~(size_t)255;
    return p;
  };
  _Float16* h0h  = (_Float16*)alloc((size_t)N * hid * 2);
  _Float16* t1h  = (_Float16*)alloc((size_t)N * hid * 2);   // pre-scaled by dinv
  _Float16* h1h  = (_Float16*)alloc((size_t)N * hid * 2);
  _Float16* t2h  = (_Float16*)alloc((size_t)N * hid * 2);   // pre-scaled by dinv
  _Float16* W1t  = (_Float16*)alloc((size_t)in_dim * hid * 2);
  _Float16* Wg1t = (_Float16*)alloc((size_t)hid * hid * 2);
  _Float16* Wg2t = (_Float16*)alloc((size_t)hid * hid * 2);
  float* agg2    = (float*)alloc((size_t)Batch * hid * 4);
  float* h3      = (float*)alloc((size_t)Batch * out_dim * 4);
  float* dinv    = (float*)alloc((size_t)N * 4);
  int*   cnt     = (int*)alloc((size_t)N * 4);
  int*   rowp    = (int*)alloc((size_t)(N + 1) * 4);
  int*   bsum    = (int*)alloc((size_t)1024 * 4);
  int*   cursor  = (int*)alloc((size_t)N * 4);
  int*   csrs    = (int*)alloc((size_t)E * 4);
  (void)ws_size; (void)n_in;

  dim3 blk(256);
  const int nb = (N + 1023) / 1024;

  // CSR + norm build
  k_zero_int<<<(N + 255) / 256, blk, 0, stream>>>(cnt, N);
  k_count<<<(E + 255) / 256, blk, 0, stream>>>(dstI, cnt, E);
  k_scan_local<<<nb, 1024, 0, stream>>>(cnt, rowp, bsum, N);
  k_scan_sums<<<1, 1024, 0, stream>>>(bsum, nb);
  k_finalize<<<(N + 255) / 256, blk, 0, stream>>>(rowp, bsum, cnt, cursor, dinv, N, E);
  k_fill<<<(E + 255) / 256, blk, 0, stream>>>(srcI, dstI, cursor, csrs, E);

  // fused weight convert + transpose (fp16)
  {
    int total = in_dim * hid + 2 * hid * hid;
    k_w_convert_all<<<(total + 255) / 256, blk, 0, stream>>>(W1, Wg1, Wg2, W1t, Wg1t, Wg2t, in_dim, hid);
  }

  dim3 gemm_grid(hid / 128, (N + 63) / 64);
  // h0 = relu(x @ W1 + b1)
  k_gemm_mfma<float, 1, 1, 0><<<gemm_grid, blk, 0, stream>>>(x, W1t, b1, nullptr, h0h, N, hid, in_dim);
  // t1' = (h0 @ Wg1) * dinv[row]
  k_gemm_mfma<_Float16, 0, 0, 1><<<gemm_grid, blk, 0, stream>>>(h0h, Wg1t, nullptr, dinv, t1h, N, hid, hid);
  // h1 = (t1'[i] + sum t1'[src]) * dinv[i] + bg1   (fp16 out)
  k_agg<_Float16><<<(N + 3) / 4, blk, 0, stream>>>(t1h, rowp, csrs, dinv, bg1, h1h, N);
  // t2' = (h1 @ Wg2) * dinv[row]
  k_gemm_mfma<_Float16, 0, 0, 1><<<gemm_grid, blk, 0, stream>>>(h1h, Wg2t, nullptr, dinv, t2h, N, hid, hid);
  // conv2 aggregation only for rows [0, Batch)  (fp32 out)
  k_agg<float><<<(Batch + 3) / 4, blk, 0, stream>>>(t2h, rowp, csrs, dinv, bg2, agg2, Batch);
  // h3 = relu(agg2 @ W2 + b2)
  k_gemm<1, 1><<<dim3(out_dim / 64, (Batch + 63) / 64), blk, 0, stream>>>(agg2, W2, b2, h3, Batch, out_dim, hid);
  // logits = h3 @ Wc + bc
  k_cls<<<(Batch + 255) / 256, blk, 0, stream>>>(h3, Wc, bc, out, Batch, out_dim);
}

// Round 2
// 538.758 us; speedup vs baseline: 1.0105x; 1.0105x over previous
//
#include <hip/hip_runtime.h>
#include <hip/hip_bf16.h>
#include <cstdint>
#include <cstddef>
#include <type_traits>

typedef _Float16 half8 __attribute__((ext_vector_type(8)));
typedef _Float16 half4v __attribute__((ext_vector_type(4)));
typedef float float4v __attribute__((ext_vector_type(4)));

// ---------------- CSR build ----------------

__global__ void k_zero_int(int* __restrict__ p, int n) {
  int i = blockIdx.x * blockDim.x + threadIdx.x;
  if (i < n) p[i] = 0;
}

__global__ void k_count(const int* __restrict__ dst, int* __restrict__ cnt, int E) {
  int e = blockIdx.x * blockDim.x + threadIdx.x;
  if (e < E) atomicAdd(&cnt[dst[e]], 1);
}

// hierarchical exclusive scan: local (per-1024 block) -> sums -> fixup
__global__ __launch_bounds__(1024) void k_scan_local(const int* __restrict__ cnt,
                                                     int* __restrict__ rowp,
                                                     int* __restrict__ bsum, int n) {
  __shared__ int sm[1024];
  int tid = threadIdx.x;
  int i = blockIdx.x * 1024 + tid;
  int v = (i < n) ? cnt[i] : 0;
  sm[tid] = v;
  __syncthreads();
  for (int off = 1; off < 1024; off <<= 1) {
    int t = (tid >= off) ? sm[tid - off] : 0;
    __syncthreads();
    sm[tid] += t;
    __syncthreads();
  }
  if (i < n) rowp[i] = sm[tid] - v;  // exclusive (pre-fixup)
  if (tid == 1023) bsum[blockIdx.x] = sm[1023];
}

__global__ __launch_bounds__(1024) void k_scan_sums(int* __restrict__ bsum, int nb) {
  __shared__ int sm[1024];
  int tid = threadIdx.x;
  int v = (tid < nb) ? bsum[tid] : 0;
  sm[tid] = v;
  __syncthreads();
  for (int off = 1; off < 1024; off <<= 1) {
    int t = (tid >= off) ? sm[tid - off] : 0;
    __syncthreads();
    sm[tid] += t;
    __syncthreads();
  }
  if (tid < nb) bsum[tid] = sm[tid] - v;  // exclusive
}

// fixup + cursor copy + dinv, fused
__global__ void k_finalize(int* __restrict__ rowp, const int* __restrict__ bsum,
                           const int* __restrict__ cnt, int* __restrict__ cursor,
                           float* __restrict__ dinv, int n, int E) {
  int i = blockIdx.x * blockDim.x + threadIdx.x;
  if (i < n) {
    int v = rowp[i] + bsum[i >> 10];
    rowp[i] = v;
    cursor[i] = v;
    dinv[i] = rsqrtf((float)(cnt[i] + 1));  // +1 self loop
  }
  if (i == 0) rowp[n] = E;
}

__global__ void k_fill(const int* __restrict__ src, const int* __restrict__ dst,
                       int* __restrict__ cursor, int* __restrict__ csr_src, int E) {
  int e = blockIdx.x * blockDim.x + threadIdx.x;
  if (e < E) {
    int pos = atomicAdd(&cursor[dst[e]], 1);
    csr_src[pos] = src[e];
  }
}

// ---------------- fused weight convert+transpose (3 matrices in one launch) --------

__global__ void k_w_convert_all(const float* __restrict__ W1, const float* __restrict__ Wg1,
                                const float* __restrict__ Wg2, _Float16* __restrict__ W1t,
                                _Float16* __restrict__ Wg1t, _Float16* __restrict__ Wg2t,
                                int in_dim, int hid) {
  int idx = blockIdx.x * blockDim.x + threadIdx.x;
  int n1 = in_dim * hid;
  int n2 = hid * hid;
  if (idx < n1) {
    int n = idx / in_dim, k = idx - n * in_dim;
    W1t[idx] = (_Float16)W1[(size_t)k * hid + n];
  } else if (idx < n1 + n2) {
    int i2 = idx - n1;
    int n = i2 / hid, k = i2 - n * hid;
    Wg1t[i2] = (_Float16)Wg1[(size_t)k * hid + n];
  } else if (idx < n1 + 2 * n2) {
    int i2 = idx - n1 - n2;
    int n = i2 / hid, k = i2 - n * hid;
    Wg2t[i2] = (_Float16)Wg2[(size_t)k * hid + n];
  }
}

// ---------------- fp16 MFMA GEMM, m97-structure ----------------
// 128x128 tile, BK=32, 4 waves (2x2), per-wave 64x64 = 4x4 fragments of 16x16x32.
// Staging: global_load_lds dwordx4 (async DMA -> LDS, linear layout, no reg round
// trip). T3-min 2-phase loop: issue next tile's DMA at loop top, compute current
// tile, ONE __syncthreads (compiler emits vmcnt(0)+lgkmcnt(0) drain) per k-step.
// DMA latency is hidden under the ds_read+cvt+MFMA phase + cross-block overlap
// (~3 blocks/CU). LDS left LINEAR: T2 swizzle is measured-null in the 2-phase
// regime (gate table), and m97 hit 874 TF with the same conflicts.
// For AT=float (GEMM1): A staged RAW fp32 (16KB/buf) and converted to fp16 after
// the fragment ds_read (global_load_lds cannot convert).
// NOTE: no device lambdas (clang-22 frontend crash in round 3 of prior session).

__device__ __forceinline__ void gl_lds16(const void* g, void* l) {
  __builtin_amdgcn_global_load_lds(
      (const __attribute__((address_space(1))) void*)g,
      (__attribute__((address_space(3))) void*)l, 16, 0, 0);
}

template <typename AT, int RELU, int BIAS, int SCALE>
__global__ __launch_bounds__(256, 3) void k_gemm_mfma(const AT* __restrict__ A,
                                                      const _Float16* __restrict__ Bt,
                                                      const float* __restrict__ bias,
                                                      const float* __restrict__ rowscale,
                                                      _Float16* __restrict__ out,
                                                      int M, int N, int K, int gx) {
  __shared__ alignas(16) AT Asm[2][128 * 32];
  __shared__ alignas(16) _Float16 Bsm[2][128 * 32];
  constexpr int RA = (int)sizeof(AT);              // DMA rounds for A: 4 (f32) / 2 (f16)
  constexpr int ABUFB = 128 * 32 * (int)sizeof(AT);
  constexpr int BBUFB = 128 * 32 * 2;

  const int tid = threadIdx.x;
  const int wv = tid >> 6;
  const int ln = tid & 63;
  const int quad = ln >> 4;
  const int l15 = ln & 15;
  const int wm = (wv >> 1) * 64;   // 0 or 64
  const int wn = (wv & 1) * 64;    // 0 or 64

  // bijective XCD-aware block swizzle (m204; works for any nwg)
  const int nwg = (int)gridDim.x;
  const int orig = (int)blockIdx.x;
  const int q = nwg >> 3, r = nwg & 7;
  const int xcd = orig & 7, idx = orig >> 3;
  const int wg = (xcd < r ? xcd * (q + 1) : r * (q + 1) + (xcd - r) * q) + idx;
  const int bx = wg % gx;
  const int by = wg / gx;
  const int bm = by * 128;
  const int bn = bx * 128;

  // ---- per-thread DMA source/dest precompute ----
  // A tile buf: 128 rows x 32 elems, linear. bytes/row = 32*sizeof(AT).
  // round rr, wave wv covers LDS bytes [rr*4096 + wv*1024, +1024); lane ln -> +ln*16.
  const char* aSrcB[RA];
  int aDstOff[RA];
#pragma unroll
  for (int rr = 0; rr < RA; ++rr) {
    int p = rr * 4096 + wv * 1024 + ln * 16;            // byte pos in A buf
    int row = p / (32 * (int)sizeof(AT));
    int colB = p - row * 32 * (int)sizeof(AT);
    int grow = bm + row; if (grow > M - 1) grow = M - 1; // clamp (epilogue masks r>=M)
    aSrcB[rr] = (const char*)(A + (size_t)grow * K) + colB;
    aDstOff[rr] = rr * 4096 + wv * 1024;                // wave-uniform (lane offset is HW)
  }
  const char* bSrcB[2];
  int bDstOff[2];
#pragma unroll
  for (int rr = 0; rr < 2; ++rr) {
    int p = rr * 4096 + wv * 1024 + ln * 16;            // byte pos in B buf (8KB)
    int row = p >> 6;                                   // 64B rows
    int colB = p & 63;
    bSrcB[rr] = (const char*)(Bt + (size_t)(bn + row) * K) + colB;
    bDstOff[rr] = rr * 4096 + wv * 1024;
  }

  float4v acc[4][4];
#pragma unroll
  for (int i = 0; i < 4; ++i)
#pragma unroll
    for (int j = 0; j < 4; ++j) acc[i][j] = (float4v){0.f, 0.f, 0.f, 0.f};

  const int nk = K >> 5;

  // prologue: DMA tile 0 -> buf 0
  {
    char* abase = (char*)&Asm[0][0];
    char* bbase = (char*)&Bsm[0][0];
#pragma unroll
    for (int rr = 0; rr < RA; ++rr) gl_lds16(aSrcB[rr], abase + aDstOff[rr]);
#pragma unroll
    for (int rr = 0; rr < 2; ++rr) gl_lds16(bSrcB[rr], bbase + bDstOff[rr]);
  }
  __syncthreads();  // vmcnt(0) drain: tile 0 resident

  int buf = 0;
  for (int kt = 0; kt < nk; ++kt) {
    // issue next tile's DMA first (latency hides under compute below)
    if (kt + 1 < nk) {
      const size_t advA = (size_t)(kt + 1) * 32 * sizeof(AT);
      const size_t advB = (size_t)(kt + 1) * 64;
      char* abase = (char*)&Asm[0][0] + (buf ^ 1) * ABUFB;
      char* bbase = (char*)&Bsm[0][0] + (buf ^ 1) * BBUFB;
#pragma unroll
      for (int rr = 0; rr < RA; ++rr) gl_lds16(aSrcB[rr] + advA, abase + aDstOff[rr]);
#pragma unroll
      for (int rr = 0; rr < 2; ++rr) gl_lds16(bSrcB[rr] + advB, bbase + bDstOff[rr]);
    }

    // compute current tile
    const AT* Ab = &Asm[buf][0];
    const _Float16* Bb = &Bsm[buf][0];
    half8 af[4], bf[4];
#pragma unroll
    for (int i = 0; i < 4; ++i) {
      int rowa = wm + i * 16 + l15;
      if constexpr (std::is_same_v<AT, float>) {
        float4v f0 = *(const float4v*)(Ab + rowa * 32 + quad * 8);
        float4v f1 = *(const float4v*)(Ab + rowa * 32 + quad * 8 + 4);
        half8 h;
        h[0] = (_Float16)f0[0]; h[1] = (_Float16)f0[1];
        h[2] = (_Float16)f0[2]; h[3] = (_Float16)f0[3];
        h[4] = (_Float16)f1[0]; h[5] = (_Float16)f1[1];
        h[6] = (_Float16)f1[2]; h[7] = (_Float16)f1[3];
        af[i] = h;
      } else {
        af[i] = *(const half8*)(Ab + rowa * 32 + quad * 8);
      }
    }
#pragma unroll
    for (int j = 0; j < 4; ++j)
      bf[j] = *(const half8*)(Bb + (wn + j * 16 + l15) * 32 + quad * 8);
#pragma unroll
    for (int i = 0; i < 4; ++i)
#pragma unroll
      for (int j = 0; j < 4; ++j)
        acc[i][j] = __builtin_amdgcn_mfma_f32_16x16x32_f16(af[i], bf[j], acc[i][j], 0, 0, 0);

    __syncthreads();  // drains vmcnt(0): next tile resident; also fences LDS reuse
    buf ^= 1;
  }

  // epilogue: C/D layout col=lane&15, row=quad*4+reg
#pragma unroll
  for (int j = 0; j < 4; ++j) {
    int c = bn + wn + j * 16 + l15;
    float bv = BIAS ? bias[c] : 0.f;
#pragma unroll
    for (int i = 0; i < 4; ++i) {
      int rbase = bm + wm + i * 16 + quad * 4;
      float4v a = acc[i][j];
#pragma unroll
      for (int reg = 0; reg < 4; ++reg) {
        int rr2 = rbase + reg;
        if (rr2 < M) {
          float v = a[reg] + bv;
          if (RELU) v = fmaxf(v, 0.f);
          if (SCALE) v *= rowscale[rr2];
          out[(size_t)rr2 * N + c] = (_Float16)v;
        }
      }
    }
  }
}

// ---------------- fp32 tiled GEMM (tail): C = act(A @ B + bias) ----------------

template <int RELU, int BIAS>
__global__ __launch_bounds__(256) void k_gemm(const float* __restrict__ A,
                                              const float* __restrict__ B,
                                              const float* __restrict__ bias,
                                              float* __restrict__ C,
                                              int M, int N, int K) {
  __shared__ float As[16][68];
  __shared__ float Bs[16][68];
  const int bm = blockIdx.y * 64;
  const int bn = blockIdx.x * 64;
  const int tid = threadIdx.x;
  const int tr = (tid >> 4) << 2;
  const int tc = (tid & 15) << 2;
  const int lm  = tid >> 2;
  const int lk  = (tid & 3) << 2;
  const int lk2 = tid >> 4;
  const int ln  = (tid & 15) << 2;
  const bool arow_ok = (bm + lm) < M;
  const float* Aptr = A + (size_t)(bm + lm) * K + lk;
  const float* Bptr = B + (size_t)lk2 * N + bn + ln;
  float acc[4][4] = {};
  for (int k0 = 0; k0 < K; k0 += 16) {
    float4 a4 = make_float4(0.f, 0.f, 0.f, 0.f);
    if (arow_ok) a4 = *(const float4*)(Aptr + k0);
    float4 b4 = *(const float4*)(Bptr + (size_t)k0 * N);
    As[lk + 0][lm] = a4.x;
    As[lk + 1][lm] = a4.y;
    As[lk + 2][lm] = a4.z;
    As[lk + 3][lm] = a4.w;
    *(float4*)&Bs[lk2][ln] = b4;
    __syncthreads();
#pragma unroll
    for (int k = 0; k < 16; ++k) {
      float4 av = *(const float4*)&As[k][tr];
      float4 bv = *(const float4*)&Bs[k][tc];
      float a[4] = {av.x, av.y, av.z, av.w};
      float b[4] = {bv.x, bv.y, bv.z, bv.w};
#pragma unroll
      for (int i = 0; i < 4; ++i)
#pragma unroll
        for (int j = 0; j < 4; ++j) acc[i][j] += a[i] * b[j];
    }
    __syncthreads();
  }
  float bias_v[4] = {0.f, 0.f, 0.f, 0.f};
  if (BIAS) {
    float4 bb = *(const float4*)(bias + bn + tc);
    bias_v[0] = bb.x; bias_v[1] = bb.y; bias_v[2] = bb.z; bias_v[3] = bb.w;
  }
#pragma unroll
  for (int i = 0; i < 4; ++i) {
    int r = bm + tr + i;
    if (r < M) {
      float4 o;
      o.x = acc[i][0] + bias_v[0];
      o.y = acc[i][1] + bias_v[1];
      o.z = acc[i][2] + bias_v[2];
      o.w = acc[i][3] + bias_v[3];
      if (RELU) {
        o.x = fmaxf(o.x, 0.f); o.y = fmaxf(o.y, 0.f);
        o.z = fmaxf(o.z, 0.f); o.w = fmaxf(o.w, 0.f);
      }
      *(float4*)&C[(size_t)r * N + bn + tc] = o;
    }
  }
}

// ---------------- GCN aggregation (gather, one wave/node, 256 feats) ----------------
// t is PRE-SCALED: t'[i] = t[i]*dinv[i].  out[i] = (t'[i] + sum t'[src]) * dinv[i] + b

template <typename OT>
__global__ __launch_bounds__(256) void k_agg(const _Float16* __restrict__ t,
                                             const int* __restrict__ row_ptr,
                                             const int* __restrict__ csr_src,
                                             const float* __restrict__ dinv,
                                             const float* __restrict__ bias,
                                             OT* __restrict__ out, int n_nodes) {
  int w = (int)((blockIdx.x * 256 + threadIdx.x) >> 6);
  int lane = threadIdx.x & 63;
  if (w >= n_nodes) return;
  float di = dinv[w];
  half4v v = *(const half4v*)(t + (size_t)w * 256 + lane * 4);
  float ax = (float)v[0], ay = (float)v[1], az = (float)v[2], aw = (float)v[3];
  int e0 = row_ptr[w], e1 = row_ptr[w + 1];
  int e = e0;
  for (; e + 4 <= e1; e += 4) {
    int s0 = csr_src[e];
    int s1 = csr_src[e + 1];
    int s2 = csr_src[e + 2];
    int s3 = csr_src[e + 3];
    half4v u0 = *(const half4v*)(t + (size_t)s0 * 256 + lane * 4);
    half4v u1 = *(const half4v*)(t + (size_t)s1 * 256 + lane * 4);
    half4v u2 = *(const half4v*)(t + (size_t)s2 * 256 + lane * 4);
    half4v u3 = *(const half4v*)(t + (size_t)s3 * 256 + lane * 4);
    ax += (float)u0[0] + (float)u1[0] + (float)u2[0] + (float)u3[0];
    ay += (float)u0[1] + (float)u1[1] + (float)u2[1] + (float)u3[1];
    az += (float)u0[2] + (float)u1[2] + (float)u2[2] + (float)u3[2];
    aw += (float)u0[3] + (float)u1[3] + (float)u2[3] + (float)u3[3];
  }
  for (; e < e1; ++e) {
    int s = csr_src[e];
    half4v u = *(const half4v*)(t + (size_t)s * 256 + lane * 4);
    ax += (float)u[0]; ay += (float)u[1]; az += (float)u[2]; aw += (float)u[3];
  }
  const float4 b = ((const float4*)bias)[lane];
  if constexpr (std::is_same_v<OT, float>) {
    float4 o;
    o.x = ax * di + b.x; o.y = ay * di + b.y;
    o.z = az * di + b.z; o.w = aw * di + b.w;
    ((float4*)(out + (size_t)w * 256))[lane] = o;
  } else {
    half4v o;
    o[0] = (_Float16)(ax * di + b.x); o[1] = (_Float16)(ay * di + b.y);
    o[2] = (_Float16)(az * di + b.z); o[3] = (_Float16)(aw * di + b.w);
    *(half4v*)(out + (size_t)w * 256 + lane * 4) = o;
  }
}

// ---------------- classifier: out[M,2] = h[M,K] @ Wc[K,2] + bc ----------------

__global__ __launch_bounds__(256) void k_cls(const float* __restrict__ h,
                                             const float* __restrict__ Wc,
                                             const float* __restrict__ bc,
                                             float* __restrict__ out, int M, int K) {
  __shared__ float w[512];
  for (int i = threadIdx.x; i < 2 * K; i += 256) w[i] = Wc[i];
  __syncthreads();
  int i = blockIdx.x * 256 + threadIdx.x;
  if (i >= M) return;
  float a0 = bc[0], a1 = bc[1];
  const float* hr = h + (size_t)i * K;
  for (int k = 0; k < K; ++k) {
    float a = hr[k];
    a0 += a * w[2 * k];
    a1 += a * w[2 * k + 1];
  }
  out[2 * i] = a0;
  out[2 * i + 1] = a1;
}

// ---------------- launch ----------------

extern "C" void kernel_launch(void* const* d_in, const int* in_sizes, int n_in,
                              void* d_out, int out_size, void* d_ws, size_t ws_size,
                              hipStream_t stream) {
  const float* x   = (const float*)d_in[0];
  const int*   ei  = (const int*)d_in[1];
  const float* W1  = (const float*)d_in[2];
  const float* b1  = (const float*)d_in[3];
  const float* Wg1 = (const float*)d_in[4];
  const float* bg1 = (const float*)d_in[5];
  const float* Wg2 = (const float*)d_in[6];
  const float* bg2 = (const float*)d_in[7];
  const float* W2  = (const float*)d_in[8];
  const float* b2  = (const float*)d_in[9];
  const float* Wc  = (const float*)d_in[10];
  const float* bc  = (const float*)d_in[11];
  float* out = (float*)d_out;

  const int hid     = in_sizes[3];            // 256
  const int in_dim  = in_sizes[2] / hid;      // 768
  const int out_dim = in_sizes[9];            // 128
  const int N       = in_sizes[0] / in_dim;   // 50000
  const int E       = in_sizes[1] / 2;        // 800000
  const int Batch   = out_size / 2;           // 1024

  const int* srcI = ei;
  const int* dstI = ei + E;

  char* ws = (char*)d_ws;
  size_t off = 0;
  auto alloc = [&](size_t bytes) -> void* {
    void* p = ws + off;
    off = (off + bytes + 255) & ~(size_t)255;
    return p;
  };
  _Float16* h0h  = (_Float16*)alloc((size_t)N * hid * 2);
  _Float16* t1h  = (_Float16*)alloc((size_t)N * hid * 2);   // pre-scaled by dinv
  _Float16* h1h  = (_Float16*)alloc((size_t)N * hid * 2);
  _Float16* t2h  = (_Float16*)alloc((size_t)N * hid * 2);   // pre-scaled by dinv
  _Float16* W1t  = (_Float16*)alloc((size_t)in_dim * hid * 2);
  _Float16* Wg1t = (_Float16*)alloc((size_t)hid * hid * 2);
  _Float16* Wg2t = (_Float16*)alloc((size_t)hid * hid * 2);
  float* agg2    = (float*)alloc((size_t)Batch * hid * 4);
  float* h3      = (float*)alloc((size_t)Batch * out_dim * 4);
  float* dinv    = (float*)alloc((size_t)N * 4);
  int*   cnt     = (int*)alloc((size_t)N * 4);
  int*   rowp    = (int*)alloc((size_t)(N + 1) * 4);
  int*   bsum    = (int*)alloc((size_t)1024 * 4);
  int*   cursor  = (int*)alloc((size_t)N * 4);
  int*   csrs    = (int*)alloc((size_t)E * 4);
  (void)ws_size; (void)n_in;

  dim3 blk(256);
  const int nb = (N + 1023) / 1024;

  // CSR + norm build
  k_zero_int<<<(N + 255) / 256, blk, 0, stream>>>(cnt, N);
  k_count<<<(E + 255) / 256, blk, 0, stream>>>(dstI, cnt, E);
  k_scan_local<<<nb, 1024, 0, stream>>>(cnt, rowp, bsum, N);
  k_scan_sums<<<1, 1024, 0, stream>>>(bsum, nb);
  k_finalize<<<(N + 255) / 256, blk, 0, stream>>>(rowp, bsum, cnt, cursor, dinv, N, E);
  k_fill<<<(E + 255) / 256, blk, 0, stream>>>(srcI, dstI, cursor, csrs, E);

  // fused weight convert + transpose (fp16)
  {
    int total = in_dim * hid + 2 * hid * hid;
    k_w_convert_all<<<(total + 255) / 256, blk, 0, stream>>>(W1, Wg1, Wg2, W1t, Wg1t, Wg2t, in_dim, hid);
  }

  const int gx = hid / 128;                 // 2
  const int gy = (N + 127) / 128;           // 391
  const int nwg = gx * gy;                  // 782
  // h0 = relu(x @ W1 + b1)
  k_gemm_mfma<float, 1, 1, 0><<<dim3(nwg), blk, 0, stream>>>(x, W1t, b1, nullptr, h0h, N, hid, in_dim, gx);
  // t1' = (h0 @ Wg1) * dinv[row]
  k_gemm_mfma<_Float16, 0, 0, 1><<<dim3(nwg), blk, 0, stream>>>(h0h, Wg1t, nullptr, dinv, t1h, N, hid, hid, gx);
  // h1 = (t1'[i] + sum t1'[src]) * dinv[i] + bg1   (fp16 out)
  k_agg<_Float16><<<(N + 3) / 4, blk, 0, stream>>>(t1h, rowp, csrs, dinv, bg1, h1h, N);
  // t2' = (h1 @ Wg2) * dinv[row]
  k_gemm_mfma<_Float16, 0, 0, 1><<<dim3(nwg), blk, 0, stream>>>(h1h, Wg2t, nullptr, dinv, t2h, N, hid, hid, gx);
  // conv2 aggregation only for rows [0, Batch)  (fp32 out)
  k_agg<float><<<(Batch + 3) / 4, blk, 0, stream>>>(t2h, rowp, csrs, dinv, bg2, agg2, Batch);
  // h3 = relu(agg2 @ W2 + b2)
  k_gemm<1, 1><<<dim3(out_dim / 64, (Batch + 63) / 64), blk, 0, stream>>>(agg2, W2, b2, h3, Batch, out_dim, hid);
  // logits = h3 @ Wc + bc
  k_cls<<<(Batch + 255) / 256, blk, 0, stream>>>(h3, Wc, bc, out, Batch, out_dim);
}

// Round 3
// 535.063 us; speedup vs baseline: 1.0175x; 1.0069x over previous
//
#include <hip/hip_runtime.h>
#include <hip/hip_bf16.h>
#include <cstdint>
#include <cstddef>
#include <type_traits>

typedef _Float16 half8 __attribute__((ext_vector_type(8)));
typedef _Float16 half4v __attribute__((ext_vector_type(4)));
typedef float float4v __attribute__((ext_vector_type(4)));

// ---------------- CSR build ----------------

__global__ void k_zero_int(int* __restrict__ p, int n) {
  int i = blockIdx.x * blockDim.x + threadIdx.x;
  if (i < n) p[i] = 0;
}

__global__ void k_count(const int* __restrict__ dst, int* __restrict__ cnt, int E) {
  int e = blockIdx.x * blockDim.x + threadIdx.x;
  if (e < E) atomicAdd(&cnt[dst[e]], 1);
}

// hierarchical exclusive scan: local (per-1024 block) -> sums -> fixup
__global__ __launch_bounds__(1024) void k_scan_local(const int* __restrict__ cnt,
                                                     int* __restrict__ rowp,
                                                     int* __restrict__ bsum, int n) {
  __shared__ int sm[1024];
  int tid = threadIdx.x;
  int i = blockIdx.x * 1024 + tid;
  int v = (i < n) ? cnt[i] : 0;
  sm[tid] = v;
  __syncthreads();
  for (int off = 1; off < 1024; off <<= 1) {
    int t = (tid >= off) ? sm[tid - off] : 0;
    __syncthreads();
    sm[tid] += t;
    __syncthreads();
  }
  if (i < n) rowp[i] = sm[tid] - v;  // exclusive (pre-fixup)
  if (tid == 1023) bsum[blockIdx.x] = sm[1023];
}

__global__ __launch_bounds__(1024) void k_scan_sums(int* __restrict__ bsum, int nb) {
  __shared__ int sm[1024];
  int tid = threadIdx.x;
  int v = (tid < nb) ? bsum[tid] : 0;
  sm[tid] = v;
  __syncthreads();
  for (int off = 1; off < 1024; off <<= 1) {
    int t = (tid >= off) ? sm[tid - off] : 0;
    __syncthreads();
    sm[tid] += t;
    __syncthreads();
  }
  if (tid < nb) bsum[tid] = sm[tid] - v;  // exclusive
}

// fixup + cursor copy + dinv, fused
__global__ void k_finalize(int* __restrict__ rowp, const int* __restrict__ bsum,
                           const int* __restrict__ cnt, int* __restrict__ cursor,
                           float* __restrict__ dinv, int n, int E) {
  int i = blockIdx.x * blockDim.x + threadIdx.x;
  if (i < n) {
    int v = rowp[i] + bsum[i >> 10];
    rowp[i] = v;
    cursor[i] = v;
    dinv[i] = rsqrtf((float)(cnt[i] + 1));  // +1 self loop
  }
  if (i == 0) rowp[n] = E;
}

__global__ void k_fill(const int* __restrict__ src, const int* __restrict__ dst,
                       int* __restrict__ cursor, int* __restrict__ csr_src, int E) {
  int e = blockIdx.x * blockDim.x + threadIdx.x;
  if (e < E) {
    int pos = atomicAdd(&cursor[dst[e]], 1);
    csr_src[pos] = src[e];
  }
}

// ---------------- fused weight convert+transpose (3 matrices in one launch) --------

__global__ void k_w_convert_all(const float* __restrict__ W1, const float* __restrict__ Wg1,
                                const float* __restrict__ Wg2, _Float16* __restrict__ W1t,
                                _Float16* __restrict__ Wg1t, _Float16* __restrict__ Wg2t,
                                int in_dim, int hid) {
  int idx = blockIdx.x * blockDim.x + threadIdx.x;
  int n1 = in_dim * hid;
  int n2 = hid * hid;
  if (idx < n1) {
    int n = idx / in_dim, k = idx - n * in_dim;
    W1t[idx] = (_Float16)W1[(size_t)k * hid + n];
  } else if (idx < n1 + n2) {
    int i2 = idx - n1;
    int n = i2 / hid, k = i2 - n * hid;
    Wg1t[i2] = (_Float16)Wg1[(size_t)k * hid + n];
  } else if (idx < n1 + 2 * n2) {
    int i2 = idx - n1 - n2;
    int n = i2 / hid, k = i2 - n * hid;
    Wg2t[i2] = (_Float16)Wg2[(size_t)k * hid + n];
  }
}

// ---------------- fp16 MFMA GEMM, 256x256 tile (full N), BK=32 ----------------
// Why: previous 128x128 tiling staged 24KB per k-step for 1.05 MF (43 FLOP/B) and
// staged every A panel twice (gx=2) -> the whole (co-resident) grid ran staging-
// cadence-limited at ~6% MfmaUtil. 256x256 stages A ONCE grid-wide and doubles
// per-block intensity (87 FLOP/B). 512 threads = 8 waves (2x4), wave tile 128x64
// (acc 8x4 f32x4 = 128 VGPR). 2-phase loop: issue next tile's global_load_lds DMA,
// compute current, one __syncthreads (vmcnt0 drain after compute covers DMA lat).
// fp32 A (GEMM1) is staged RAW, but SPLIT into two 16-float half-buffers so LDS
// rows are 64B (8-way bank alias like m97) instead of 128B (32-way). The split is
// done by PRE-PERMUTING the per-lane global source; LDS dest stays linear (m173).
// fp16 A (GEMM2/3) stays fully linear (64B rows already).
// NOTE: no device lambdas (clang-22 frontend crash in earlier session).

__device__ __forceinline__ void gl_lds16(const void* g, void* l) {
  __builtin_amdgcn_global_load_lds(
      (const __attribute__((address_space(1))) void*)g,
      (__attribute__((address_space(3))) void*)l, 16, 0, 0);
}

template <typename AT, int RELU, int BIAS, int SCALE>
__global__ __launch_bounds__(512) void k_gemm_mfma(const AT* __restrict__ A,
                                                   const _Float16* __restrict__ Bt,
                                                   const float* __restrict__ bias,
                                                   const float* __restrict__ rowscale,
                                                   _Float16* __restrict__ out,
                                                   int M, int N, int K) {
  // A buf: 256 rows x 32 elems; fp32 split-half layout (see header comment).
  __shared__ alignas(16) AT Asm[2][256 * 32];
  __shared__ alignas(16) _Float16 Bsm[2][256 * 32];
  constexpr bool AF32 = std::is_same_v<AT, float>;
  constexpr int RA = AF32 ? 4 : 2;                   // DMA rounds for A (8KB/round)
  constexpr int ABUFB = 256 * 32 * (int)sizeof(AT);  // 32KB / 16KB
  constexpr int BBUFB = 256 * 32 * 2;                // 16KB

  const int tid = threadIdx.x;
  const int wv = tid >> 6;          // 0..7
  const int ln = tid & 63;
  const int quad = ln >> 4;
  const int l15 = ln & 15;
  const int wm = (wv >> 2) * 128;   // 0 or 128
  const int wn = (wv & 3) * 64;     // 0,64,128,192

  const int bm = (int)blockIdx.x * 256;

  // ---- per-thread DMA source precompute (dest is linear; source pre-permuted) ----
  const char* aSrcB[RA];
  int aDstOff[RA];
#pragma unroll
  for (int rr = 0; rr < RA; ++rr) {
    int q = rr * 8192 + wv * 1024 + ln * 16;  // byte pos in A buf
    int row, colE;                            // colE in elements
    if constexpr (AF32) {
      int h = q >> 14;                        // half-buffer (cols 0-15 | 16-31)
      row = (q >> 6) & 255;
      colE = ((q & 63) >> 2) + (h << 4);
    } else {
      row = q >> 6;
      colE = (q & 63) >> 1;
    }
    int grow = bm + row; if (grow > M - 1) grow = M - 1;  // clamp; epilogue masks
    aSrcB[rr] = (const char*)(A + (size_t)grow * K + colE);
    aDstOff[rr] = rr * 8192 + wv * 1024;      // wave-uniform (lane*16 added by HW)
  }
  const char* bSrcB[2];
  int bDstOff[2];
#pragma unroll
  for (int rr = 0; rr < 2; ++rr) {
    int q = rr * 8192 + wv * 1024 + ln * 16;  // byte pos in B buf
    int row = q >> 6;
    int colH = (q & 63) >> 1;
    bSrcB[rr] = (const char*)(Bt + (size_t)row * K + colH);
    bDstOff[rr] = rr * 8192 + wv * 1024;
  }

  float4v acc[8][4];
#pragma unroll
  for (int i = 0; i < 8; ++i)
#pragma unroll
    for (int j = 0; j < 4; ++j) acc[i][j] = (float4v){0.f, 0.f, 0.f, 0.f};

  const int nk = K >> 5;

  // prologue: DMA tile 0 -> buf 0
  {
    char* abase = (char*)&Asm[0][0];
    char* bbase = (char*)&Bsm[0][0];
#pragma unroll
    for (int rr = 0; rr < RA; ++rr) gl_lds16(aSrcB[rr], abase + aDstOff[rr]);
#pragma unroll
    for (int rr = 0; rr < 2; ++rr) gl_lds16(bSrcB[rr], bbase + bDstOff[rr]);
  }
  __syncthreads();  // vmcnt(0) drain: tile 0 resident

  int buf = 0;
  for (int kt = 0; kt < nk; ++kt) {
    // issue next tile's DMA first (latency hides under compute below)
    if (kt + 1 < nk) {
      const size_t advA = (size_t)(kt + 1) * 32 * sizeof(AT);
      const size_t advB = (size_t)(kt + 1) * 64;
      char* abase = (char*)&Asm[0][0] + (buf ^ 1) * ABUFB;
      char* bbase = (char*)&Bsm[0][0] + (buf ^ 1) * BBUFB;
#pragma unroll
      for (int rr = 0; rr < RA; ++rr) gl_lds16(aSrcB[rr] + advA, abase + aDstOff[rr]);
#pragma unroll
      for (int rr = 0; rr < 2; ++rr) gl_lds16(bSrcB[rr] + advB, bbase + bDstOff[rr]);
    }

    // compute current tile
    const AT* Ab = &Asm[buf][0];
    const _Float16* Bb = &Bsm[buf][0];
    half8 bf[4];
#pragma unroll
    for (int j = 0; j < 4; ++j)
      bf[j] = *(const half8*)(Bb + (wn + j * 16 + l15) * 32 + quad * 8);
#pragma unroll
    for (int i = 0; i < 8; ++i) {
      int rowa = wm + i * 16 + l15;
      half8 af;
      if constexpr (AF32) {
        // split-half: cols quad*8..quad*8+7 live in half (quad>>1), sub (quad&1)
        const float* ap = Ab + (quad >> 1) * 4096 + rowa * 16 + (quad & 1) * 8;
        float4v f0 = *(const float4v*)ap;
        float4v f1 = *(const float4v*)(ap + 4);
        af[0] = (_Float16)f0[0]; af[1] = (_Float16)f0[1];
        af[2] = (_Float16)f0[2]; af[3] = (_Float16)f0[3];
        af[4] = (_Float16)f1[0]; af[5] = (_Float16)f1[1];
        af[6] = (_Float16)f1[2]; af[7] = (_Float16)f1[3];
      } else {
        af = *(const half8*)(Ab + rowa * 32 + quad * 8);
      }
#pragma unroll
      for (int j = 0; j < 4; ++j)
        acc[i][j] = __builtin_amdgcn_mfma_f32_16x16x32_f16(af, bf[j], acc[i][j], 0, 0, 0);
    }

    __syncthreads();  // drains vmcnt(0): next tile resident; also fences LDS reuse
    buf ^= 1;
  }

  // epilogue: C/D layout col=lane&15, row=quad*4+reg
#pragma unroll
  for (int j = 0; j < 4; ++j) {
    int c = wn + j * 16 + l15;
    float bv = BIAS ? bias[c] : 0.f;
#pragma unroll
    for (int i = 0; i < 8; ++i) {
      int rbase = bm + wm + i * 16 + quad * 4;
      float4v a = acc[i][j];
#pragma unroll
      for (int reg = 0; reg < 4; ++reg) {
        int r = rbase + reg;
        if (r < M) {
          float v = a[reg] + bv;
          if (RELU) v = fmaxf(v, 0.f);
          if (SCALE) v *= rowscale[r];
          out[(size_t)r * N + c] = (_Float16)v;
        }
      }
    }
  }
}

// ---------------- fp32 tiled GEMM (tail): C = act(A @ B + bias) ----------------

template <int RELU, int BIAS>
__global__ __launch_bounds__(256) void k_gemm(const float* __restrict__ A,
                                              const float* __restrict__ B,
                                              const float* __restrict__ bias,
                                              float* __restrict__ C,
                                              int M, int N, int K) {
  __shared__ float As[16][68];
  __shared__ float Bs[16][68];
  const int bm = blockIdx.y * 64;
  const int bn = blockIdx.x * 64;
  const int tid = threadIdx.x;
  const int tr = (tid >> 4) << 2;
  const int tc = (tid & 15) << 2;
  const int lm  = tid >> 2;
  const int lk  = (tid & 3) << 2;
  const int lk2 = tid >> 4;
  const int ln  = (tid & 15) << 2;
  const bool arow_ok = (bm + lm) < M;
  const float* Aptr = A + (size_t)(bm + lm) * K + lk;
  const float* Bptr = B + (size_t)lk2 * N + bn + ln;
  float acc[4][4] = {};
  for (int k0 = 0; k0 < K; k0 += 16) {
    float4 a4 = make_float4(0.f, 0.f, 0.f, 0.f);
    if (arow_ok) a4 = *(const float4*)(Aptr + k0);
    float4 b4 = *(const float4*)(Bptr + (size_t)k0 * N);
    As[lk + 0][lm] = a4.x;
    As[lk + 1][lm] = a4.y;
    As[lk + 2][lm] = a4.z;
    As[lk + 3][lm] = a4.w;
    *(float4*)&Bs[lk2][ln] = b4;
    __syncthreads();
#pragma unroll
    for (int k = 0; k < 16; ++k) {
      float4 av = *(const float4*)&As[k][tr];
      float4 bv = *(const float4*)&Bs[k][tc];
      float a[4] = {av.x, av.y, av.z, av.w};
      float b[4] = {bv.x, bv.y, bv.z, bv.w};
#pragma unroll
      for (int i = 0; i < 4; ++i)
#pragma unroll
        for (int j = 0; j < 4; ++j) acc[i][j] += a[i] * b[j];
    }
    __syncthreads();
  }
  float bias_v[4] = {0.f, 0.f, 0.f, 0.f};
  if (BIAS) {
    float4 bb = *(const float4*)(bias + bn + tc);
    bias_v[0] = bb.x; bias_v[1] = bb.y; bias_v[2] = bb.z; bias_v[3] = bb.w;
  }
#pragma unroll
  for (int i = 0; i < 4; ++i) {
    int r = bm + tr + i;
    if (r < M) {
      float4 o;
      o.x = acc[i][0] + bias_v[0];
      o.y = acc[i][1] + bias_v[1];
      o.z = acc[i][2] + bias_v[2];
      o.w = acc[i][3] + bias_v[3];
      if (RELU) {
        o.x = fmaxf(o.x, 0.f); o.y = fmaxf(o.y, 0.f);
        o.z = fmaxf(o.z, 0.f); o.w = fmaxf(o.w, 0.f);
      }
      *(float4*)&C[(size_t)r * N + bn + tc] = o;
    }
  }
}

// ---------------- GCN aggregation (gather, one wave/node, 256 feats) ----------------
// t is PRE-SCALED: t'[i] = t[i]*dinv[i].  out[i] = (t'[i] + sum t'[src]) * dinv[i] + b

template <typename OT>
__global__ __launch_bounds__(256) void k_agg(const _Float16* __restrict__ t,
                                             const int* __restrict__ row_ptr,
                                             const int* __restrict__ csr_src,
                                             const float* __restrict__ dinv,
                                             const float* __restrict__ bias,
                                             OT* __restrict__ out, int n_nodes) {
  int w = (int)((blockIdx.x * 256 + threadIdx.x) >> 6);
  int lane = threadIdx.x & 63;
  if (w >= n_nodes) return;
  float di = dinv[w];
  half4v v = *(const half4v*)(t + (size_t)w * 256 + lane * 4);
  float ax = (float)v[0], ay = (float)v[1], az = (float)v[2], aw = (float)v[3];
  int e0 = row_ptr[w], e1 = row_ptr[w + 1];
  int e = e0;
  for (; e + 4 <= e1; e += 4) {
    int s0 = csr_src[e];
    int s1 = csr_src[e + 1];
    int s2 = csr_src[e + 2];
    int s3 = csr_src[e + 3];
    half4v u0 = *(const half4v*)(t + (size_t)s0 * 256 + lane * 4);
    half4v u1 = *(const half4v*)(t + (size_t)s1 * 256 + lane * 4);
    half4v u2 = *(const half4v*)(t + (size_t)s2 * 256 + lane * 4);
    half4v u3 = *(const half4v*)(t + (size_t)s3 * 256 + lane * 4);
    ax += (float)u0[0] + (float)u1[0] + (float)u2[0] + (float)u3[0];
    ay += (float)u0[1] + (float)u1[1] + (float)u2[1] + (float)u3[1];
    az += (float)u0[2] + (float)u1[2] + (float)u2[2] + (float)u3[2];
    aw += (float)u0[3] + (float)u1[3] + (float)u2[3] + (float)u3[3];
  }
  for (; e < e1; ++e) {
    int s = csr_src[e];
    half4v u = *(const half4v*)(t + (size_t)s * 256 + lane * 4);
    ax += (float)u[0]; ay += (float)u[1]; az += (float)u[2]; aw += (float)u[3];
  }
  const float4 b = ((const float4*)bias)[lane];
  if constexpr (std::is_same_v<OT, float>) {
    float4 o;
    o.x = ax * di + b.x; o.y = ay * di + b.y;
    o.z = az * di + b.z; o.w = aw * di + b.w;
    ((float4*)(out + (size_t)w * 256))[lane] = o;
  } else {
    half4v o;
    o[0] = (_Float16)(ax * di + b.x); o[1] = (_Float16)(ay * di + b.y);
    o[2] = (_Float16)(az * di + b.z); o[3] = (_Float16)(aw * di + b.w);
    *(half4v*)(out + (size_t)w * 256 + lane * 4) = o;
  }
}

// ---------------- classifier: out[M,2] = h[M,K] @ Wc[K,2] + bc ----------------

__global__ __launch_bounds__(256) void k_cls(const float* __restrict__ h,
                                             const float* __restrict__ Wc,
                                             const float* __restrict__ bc,
                                             float* __restrict__ out, int M, int K) {
  __shared__ float w[512];
  for (int i = threadIdx.x; i < 2 * K; i += 256) w[i] = Wc[i];
  __syncthreads();
  int i = blockIdx.x * 256 + threadIdx.x;
  if (i >= M) return;
  float a0 = bc[0], a1 = bc[1];
  const float* hr = h + (size_t)i * K;
  for (int k = 0; k < K; ++k) {
    float a = hr[k];
    a0 += a * w[2 * k];
    a1 += a * w[2 * k + 1];
  }
  out[2 * i] = a0;
  out[2 * i + 1] = a1;
}

// ---------------- launch ----------------

extern "C" void kernel_launch(void* const* d_in, const int* in_sizes, int n_in,
                              void* d_out, int out_size, void* d_ws, size_t ws_size,
                              hipStream_t stream) {
  const float* x   = (const float*)d_in[0];
  const int*   ei  = (const int*)d_in[1];
  const float* W1  = (const float*)d_in[2];
  const float* b1  = (const float*)d_in[3];
  const float* Wg1 = (const float*)d_in[4];
  const float* bg1 = (const float*)d_in[5];
  const float* Wg2 = (const float*)d_in[6];
  const float* bg2 = (const float*)d_in[7];
  const float* W2  = (const float*)d_in[8];
  const float* b2  = (const float*)d_in[9];
  const float* Wc  = (const float*)d_in[10];
  const float* bc  = (const float*)d_in[11];
  float* out = (float*)d_out;

  const int hid     = in_sizes[3];            // 256
  const int in_dim  = in_sizes[2] / hid;      // 768
  const int out_dim = in_sizes[9];            // 128
  const int N       = in_sizes[0] / in_dim;   // 50000
  const int E       = in_sizes[1] / 2;        // 800000
  const int Batch   = out_size / 2;           // 1024

  const int* srcI = ei;
  const int* dstI = ei + E;

  char* ws = (char*)d_ws;
  size_t off = 0;
  auto alloc = [&](size_t bytes) -> void* {
    void* p = ws + off;
    off = (off + bytes + 255) & ~(size_t)255;
    return p;
  };
  _Float16* h0h  = (_Float16*)alloc((size_t)N * hid * 2);
  _Float16* t1h  = (_Float16*)alloc((size_t)N * hid * 2);   // pre-scaled by dinv
  _Float16* h1h  = (_Float16*)alloc((size_t)N * hid * 2);
  _Float16* t2h  = (_Float16*)alloc((size_t)N * hid * 2);   // pre-scaled by dinv
  _Float16* W1t  = (_Float16*)alloc((size_t)in_dim * hid * 2);
  _Float16* Wg1t = (_Float16*)alloc((size_t)hid * hid * 2);
  _Float16* Wg2t = (_Float16*)alloc((size_t)hid * hid * 2);
  float* agg2    = (float*)alloc((size_t)Batch * hid * 4);
  float* h3      = (float*)alloc((size_t)Batch * out_dim * 4);
  float* dinv    = (float*)alloc((size_t)N * 4);
  int*   cnt     = (int*)alloc((size_t)N * 4);
  int*   rowp    = (int*)alloc((size_t)(N + 1) * 4);
  int*   bsum    = (int*)alloc((size_t)1024 * 4);
  int*   cursor  = (int*)alloc((size_t)N * 4);
  int*   csrs    = (int*)alloc((size_t)E * 4);
  (void)ws_size; (void)n_in;

  dim3 blk(256);
  const int nb = (N + 1023) / 1024;

  // CSR + norm build
  k_zero_int<<<(N + 255) / 256, blk, 0, stream>>>(cnt, N);
  k_count<<<(E + 255) / 256, blk, 0, stream>>>(dstI, cnt, E);
  k_scan_local<<<nb, 1024, 0, stream>>>(cnt, rowp, bsum, N);
  k_scan_sums<<<1, 1024, 0, stream>>>(bsum, nb);
  k_finalize<<<(N + 255) / 256, blk, 0, stream>>>(rowp, bsum, cnt, cursor, dinv, N, E);
  k_fill<<<(E + 255) / 256, blk, 0, stream>>>(srcI, dstI, cursor, csrs, E);

  // fused weight convert + transpose (fp16)
  {
    int total = in_dim * hid + 2 * hid * hid;
    k_w_convert_all<<<(total + 255) / 256, blk, 0, stream>>>(W1, Wg1, Wg2, W1t, Wg1t, Wg2t, in_dim, hid);
  }

  const int ng = (N + 255) / 256;   // 196 blocks, full-N output tile
  dim3 gblk(512);
  // h0 = relu(x @ W1 + b1)
  k_gemm_mfma<float, 1, 1, 0><<<dim3(ng), gblk, 0, stream>>>(x, W1t, b1, nullptr, h0h, N, hid, in_dim);
  // t1' = (h0 @ Wg1) * dinv[row]
  k_gemm_mfma<_Float16, 0, 0, 1><<<dim3(ng), gblk, 0, stream>>>(h0h, Wg1t, nullptr, dinv, t1h, N, hid, hid);
  // h1 = (t1'[i] + sum t1'[src]) * dinv[i] + bg1   (fp16 out)
  k_agg<_Float16><<<(N + 3) / 4, blk, 0, stream>>>(t1h, rowp, csrs, dinv, bg1, h1h, N);
  // t2' = (h1 @ Wg2) * dinv[row]
  k_gemm_mfma<_Float16, 0, 0, 1><<<dim3(ng), gblk, 0, stream>>>(h1h, Wg2t, nullptr, dinv, t2h, N, hid, hid);
  // conv2 aggregation only for rows [0, Batch)  (fp32 out)
  k_agg<float><<<(Batch + 3) / 4, blk, 0, stream>>>(t2h, rowp, csrs, dinv, bg2, agg2, Batch);
  // h3 = relu(agg2 @ W2 + b2)
  k_gemm<1, 1><<<dim3(out_dim / 64, (Batch + 63) / 64), blk, 0, stream>>>(agg2, W2, b2, h3, Batch, out_dim, hid);
  // logits = h3 @ Wc + bc
  k_cls<<<(Batch + 255) / 256, blk, 0, stream>>>(h3, Wc, bc, out, Batch, out_dim);
}